// Round 5
// baseline (2007.186 us; speedup 1.0000x reference)
//
#include <hip/hip_runtime.h>
#include <hip/hip_bf16.h>
#include <stdint.h>

#define HIDDEN 4096
#define INTER  14336
#define NSEL   4096

using short8 = __attribute__((ext_vector_type(8))) short;
using f32x16 = __attribute__((ext_vector_type(16))) float;

__device__ __forceinline__ uint16_t f2bf(float f) {
  uint32_t u = __float_as_uint(f);
  uint32_t r = (u + 0x7FFFu + ((u >> 16) & 1u)) >> 16;
  return (uint16_t)r;
}
__device__ __forceinline__ float bf2f(uint16_t h) {
  return __uint_as_float(((uint32_t)h) << 16);
}
__device__ __forceinline__ uint32_t pack2(float lo, float hi) {
  return (uint32_t)f2bf(lo) | ((uint32_t)f2bf(hi) << 16);
}

// ---- fp32 -> bf16 conversion, 8 elems/thread ----
__global__ void cvt_f32_bf16(const float* __restrict__ in, uint16_t* __restrict__ out) {
  size_t i = ((size_t)blockIdx.x * 256 + threadIdx.x) * 8;
  float4 a = *(const float4*)(in + i);
  float4 b = *(const float4*)(in + i + 4);
  uint4 v;
  v.x = pack2(a.x, a.y); v.y = pack2(a.z, a.w);
  v.z = pack2(b.x, b.y); v.w = pack2(b.z, b.w);
  *(uint4*)(out + i) = v;
}

// ---- gather selected tokens + cast to bf16 ----
__global__ void gather_cast(const float* __restrict__ x, const int* __restrict__ idx,
                            uint16_t* __restrict__ xs) {
  const int n = blockIdx.x;
  const int t = threadIdx.x;
  const size_t s = (size_t)idx[n] * HIDDEN + (size_t)t * 16;
  const size_t d = (size_t)n * HIDDEN + (size_t)t * 16;
  const float4* sp = (const float4*)(x + s);
  float4 f0 = sp[0], f1 = sp[1], f2 = sp[2], f3 = sp[3];
  uint4 v0, v1;
  v0.x = pack2(f0.x, f0.y); v0.y = pack2(f0.z, f0.w);
  v0.z = pack2(f1.x, f1.y); v0.w = pack2(f1.z, f1.w);
  v1.x = pack2(f2.x, f2.y); v1.y = pack2(f2.z, f2.w);
  v1.z = pack2(f3.x, f3.y); v1.w = pack2(f3.z, f3.w);
  *(uint4*)(xs + d)     = v0;
  *(uint4*)(xs + d + 8) = v1;
}

__device__ __forceinline__ void gload16(const void* g, void* l) {
  __builtin_amdgcn_global_load_lds(
      (const __attribute__((address_space(1))) void*)g,
      (__attribute__((address_space(3))) void*)l, 16, 0, 0);
}

// ============================================================================
// NT GEMM: C[M][N] = A[M][K]*B[N][K]^T, bf16 in, fp32 acc.
// 256x256 block tile, BK=16, 16 waves (4M x 4N) of 64x64, 1024 threads.
// mfma_f32_32x32x16_bf16. Ring-3 LDS (3 x (A 8KB + B 8KB) = 48 KiB).
// 16 waves/CU at <=128 regs/wave (acc 64 + operands); 1 block/CU.
// Per tile: 1 gload16/thread (waves 0-7 stage A, 8-15 stage B), 4 ds_read
// + 4 MFMA per wave, one s_barrier + counted s_waitcnt vmcnt(1).
// LDS layout (conflict-free for 32x32 frag reads, re-derived):
//   tile = 256 rows x 16 cols (u16). line(128B) = 4 rows; within a row,
//   kh in {0,1} selects the 8-col half. slot0 = (r&3)*2 + kh;
//   slot = slot0 ^ (line&7); off_u16 = line*64 + slot*8.
//   A frag read (32 rows x both kh): each 8-lane group covers 8 distinct
//   slots (<=2-way aliasing in any phasing = free). Applied via
//   pre-inverse-swizzled global source + linear gload_lds dest (rule 21).
// T1: bijective XCD swizzle, bm-fastest (concurrent blocks share B-panel).
// EPI 0: store bf16 g. EPI 1: h = silu(g)*acc overwrite (regular stores,
// reread by next GEMM). EPI 2: out = acc*wt (nontemporal, never reread).
// ============================================================================
template<int EPI>
__global__ __launch_bounds__(1024, 4) void gemm_nt(
    const uint16_t* __restrict__ A,
    const uint16_t* __restrict__ B,
    uint16_t* __restrict__ G,
    float* __restrict__ O,
    const float* __restrict__ Wt,
    int N, int K, int nbm)
{
  __shared__ __align__(16) uint16_t lds[3][8192];   // [slot][A 0..4095 | B 4096..8191]

  const int nwg = (int)gridDim.x;
  const int lid = ((int)blockIdx.x & 7) * (nwg >> 3) + ((int)blockIdx.x >> 3);
  const int bm = lid % nbm, bn = lid / nbm;

  const int tid  = (int)threadIdx.x;
  const int lane = tid & 63, w = tid >> 6;
  const int wm = w >> 2, wn = w & 3;       // wave tile: rows wm*64, cols wn*64
  const int l31 = lane & 31, kh = lane >> 5;

  // fragment read offsets (u16, slot-relative), swizzled
  int offA[2], offB[2];
#pragma unroll
  for (int m = 0; m < 2; ++m) {
    const int r  = wm * 64 + m * 32 + l31;
    const int ln = r >> 2;
    const int s0 = (r & 3) * 2 + kh;
    offA[m] = ln * 64 + ((s0 ^ (ln & 7)) * 8);
  }
#pragma unroll
  for (int n = 0; n < 2; ++n) {
    const int r  = wn * 64 + n * 32 + l31;
    const int ln = r >> 2;
    const int s0 = (r & 3) * 2 + kh;
    offB[n] = 4096 + ln * 64 + ((s0 ^ (ln & 7)) * 8);
  }

  // staging: thread covers one 16B chunk of A (tid<512) or B (tid>=512);
  // inverse-swizzled global source, linear gload_lds dest.
  const int j   = tid & 511, isB = tid >> 9;
  const int sln = j >> 3;
  const int ss0 = (j & 7) ^ (sln & 7);
  const int sr  = sln * 4 + (ss0 >> 1);
  const int sc  = (ss0 & 1) * 8;
  const uint16_t* src = (isB ? B + (size_t)(bn * 256 + sr) * K
                             : A + (size_t)(bm * 256 + sr) * K) + sc;
  const int ldsOff = isB * 4096 + j * 8;

#define STAGE(tt, s) gload16(src + (size_t)(tt) * 16, &lds[s][ldsOff])

  f32x16 acc[2][2];
#pragma unroll
  for (int m = 0; m < 2; ++m)
#pragma unroll
    for (int n = 0; n < 2; ++n)
#pragma unroll
      for (int q = 0; q < 16; ++q) acc[m][n][q] = 0.f;

  const int nk = K >> 4;

  // prologue: stage tiles 0,1; certify tile 0 (tile 1's load in flight)
  STAGE(0, 0);
  STAGE(1, 1);
  asm volatile("s_waitcnt vmcnt(1)" ::: "memory");
  __builtin_amdgcn_s_barrier();

  int sc_ = 0, sp_ = 2;   // current slot, stage slot (t+2)
  for (int t = 0; t < nk; ++t) {
    const uint16_t* S = &lds[sc_][0];

    if (t + 2 < nk) STAGE(t + 2, sp_);

    short8 a0 = *(const short8*)&S[offA[0]];
    short8 a1 = *(const short8*)&S[offA[1]];
    short8 b0 = *(const short8*)&S[offB[0]];
    short8 b1 = *(const short8*)&S[offB[1]];
    __builtin_amdgcn_s_setprio(1);
    acc[0][0] = __builtin_amdgcn_mfma_f32_32x32x16_bf16(a0, b0, acc[0][0], 0, 0, 0);
    acc[0][1] = __builtin_amdgcn_mfma_f32_32x32x16_bf16(a0, b1, acc[0][1], 0, 0, 0);
    acc[1][0] = __builtin_amdgcn_mfma_f32_32x32x16_bf16(a1, b0, acc[1][0], 0, 0, 0);
    acc[1][1] = __builtin_amdgcn_mfma_f32_32x32x16_bf16(a1, b1, acc[1][1], 0, 0, 0);
    __builtin_amdgcn_s_setprio(0);

    // certify tile t+1; keep t+2's load in flight (never drain mid-loop)
    if (t + 2 < nk) { asm volatile("s_waitcnt vmcnt(1)" ::: "memory"); }
    else            { asm volatile("s_waitcnt vmcnt(0)" ::: "memory"); }
    __builtin_amdgcn_s_barrier();

    sc_ = (sc_ == 2) ? 0 : sc_ + 1;
    sp_ = (sp_ == 2) ? 0 : sp_ + 1;
  }
#undef STAGE

  // epilogue (32x32 C/D): col=lane&31, row=(reg&3)+8*(reg>>2)+4*(lane>>5)
  const int row0 = bm * 256 + wm * 64, col0 = bn * 256 + wn * 64;
#pragma unroll
  for (int m = 0; m < 2; ++m)
#pragma unroll
    for (int n = 0; n < 2; ++n) {
      const int c = col0 + n * 32 + l31;
#pragma unroll
      for (int reg = 0; reg < 16; ++reg) {
        const int r = row0 + m * 32 + (reg & 3) + 8 * (reg >> 2) + 4 * kh;
        const float v = acc[m][n][reg];
        if constexpr (EPI == 0) {
          G[(size_t)r * N + c] = f2bf(v);
        } else if constexpr (EPI == 1) {
          float gf = bf2f(G[(size_t)r * N + c]);
          float h = gf / (1.f + __expf(-gf)) * v;
          G[(size_t)r * N + c] = f2bf(h);
        } else {
          __builtin_nontemporal_store(v * Wt[r], &O[(size_t)r * N + c]);
        }
      }
    }
}

extern "C" void kernel_launch(void* const* d_in, const int* in_sizes, int n_in,
                              void* d_out, int out_size, void* d_ws, size_t ws_size,
                              hipStream_t stream) {
  const float* x   = (const float*)d_in[0];
  const float* Wg  = (const float*)d_in[1];
  const float* Wu  = (const float*)d_in[2];
  const float* Wd  = (const float*)d_in[3];
  const int*   top = (const int*)d_in[4];
  const float* wt  = (const float*)d_in[5];
  float* out = (float*)d_out;

  const size_t NE_X = (size_t)NSEL * HIDDEN;
  const size_t NE_W = (size_t)INTER * HIDDEN;
  if (ws_size < (NE_X + 3 * NE_W) * sizeof(uint16_t)) return;

  uint16_t* xs = (uint16_t*)d_ws;
  uint16_t* w1 = xs + NE_X;
  uint16_t* w2 = w1 + NE_W;
  uint16_t* gh = w2 + NE_W;

  const int WBLK = (int)(NE_W / (256 * 8));
  const int nbm  = NSEL / 256;      // 16
  const int nbn1 = INTER / 256;     // 56
  const int nbn2 = HIDDEN / 256;    // 16

  cvt_f32_bf16<<<WBLK, 256, 0, stream>>>(Wg, w1);
  cvt_f32_bf16<<<WBLK, 256, 0, stream>>>(Wu, w2);
  gather_cast<<<NSEL, 256, 0, stream>>>(x, top, xs);

  // gate: g = x_sel * Wg^T -> gh (bf16)
  gemm_nt<0><<<nbm * nbn1, 1024, 0, stream>>>(xs, w1, gh, nullptr, nullptr,
                                              INTER, HIDDEN, nbm);
  // Wd -> w1 (after gate GEMM consumed Wg; stream-ordered)
  cvt_f32_bf16<<<WBLK, 256, 0, stream>>>(Wd, w1);
  // up + SwiGLU: h = silu(g) * (x_sel * Wu^T) -> gh in place
  gemm_nt<1><<<nbm * nbn1, 1024, 0, stream>>>(xs, w2, gh, nullptr, nullptr,
                                              INTER, HIDDEN, nbm);
  // down + routing weight: out = (h * Wd^T) * weight[:,None]
  gemm_nt<2><<<nbm * nbn2, 1024, 0, stream>>>(gh, w1, nullptr, out, wt,
                                              HIDDEN, INTER, nbm);
}

// Round 6
// 1737.324 us; speedup vs baseline: 1.1553x; 1.1553x over previous
//
#include <hip/hip_runtime.h>
#include <hip/hip_bf16.h>
#include <stdint.h>

#define HIDDEN 4096
#define INTER  14336
#define NSEL   4096

using short8 = __attribute__((ext_vector_type(8))) short;
using f32x4  = __attribute__((ext_vector_type(4))) float;

__device__ __forceinline__ uint16_t f2bf(float f) {
  uint32_t u = __float_as_uint(f);
  uint32_t r = (u + 0x7FFFu + ((u >> 16) & 1u)) >> 16;
  return (uint16_t)r;
}
__device__ __forceinline__ float bf2f(uint16_t h) {
  return __uint_as_float(((uint32_t)h) << 16);
}
__device__ __forceinline__ uint32_t pack2(float lo, float hi) {
  return (uint32_t)f2bf(lo) | ((uint32_t)f2bf(hi) << 16);
}

// ---- fp32 -> bf16 conversion, 8 elems/thread ----
__global__ void cvt_f32_bf16(const float* __restrict__ in, uint16_t* __restrict__ out) {
  size_t i = ((size_t)blockIdx.x * 256 + threadIdx.x) * 8;
  float4 a = *(const float4*)(in + i);
  float4 b = *(const float4*)(in + i + 4);
  uint4 v;
  v.x = pack2(a.x, a.y); v.y = pack2(a.z, a.w);
  v.z = pack2(b.x, b.y); v.w = pack2(b.z, b.w);
  *(uint4*)(out + i) = v;
}

// ---- gather selected tokens + cast to bf16 ----
__global__ void gather_cast(const float* __restrict__ x, const int* __restrict__ idx,
                            uint16_t* __restrict__ xs) {
  const int n = blockIdx.x;
  const int t = threadIdx.x;
  const size_t s = (size_t)idx[n] * HIDDEN + (size_t)t * 16;
  const size_t d = (size_t)n * HIDDEN + (size_t)t * 16;
  const float4* sp = (const float4*)(x + s);
  float4 f0 = sp[0], f1 = sp[1], f2 = sp[2], f3 = sp[3];
  uint4 v0, v1;
  v0.x = pack2(f0.x, f0.y); v0.y = pack2(f0.z, f0.w);
  v0.z = pack2(f1.x, f1.y); v0.w = pack2(f1.z, f1.w);
  v1.x = pack2(f2.x, f2.y); v1.y = pack2(f2.z, f2.w);
  v1.z = pack2(f3.x, f3.y); v1.w = pack2(f3.z, f3.w);
  *(uint4*)(xs + d)     = v0;
  *(uint4*)(xs + d + 8) = v1;
}

__device__ __forceinline__ void gload16(const void* g, void* l) {
  __builtin_amdgcn_global_load_lds(
      (const __attribute__((address_space(1))) void*)g,
      (__attribute__((address_space(3))) void*)l, 16, 0, 0);
}

// ============================================================================
// NT GEMM: C[M][N] = A[M][K]*B[N][K]^T, bf16 in, fp32 acc.
// 256(M) x 128(N) block tile, BK=32, 8 waves (4M x 2N) of 64x64, 512 thr.
// mfma_f32_16x16x32_bf16 (layout with MEASURED-ZERO bank conflicts, r2/r3;
// the 32x32-frag read pattern measured +4 cyc/ds_read under two different
// swizzles -> reverted). Ring-3 LDS (3 x (A 16KB + B 8KB) = 72 KiB) ->
// 2 blocks/CU, 16 waves/CU (acc 64 AGPR + ~60 VGPR <= 128 unified regs).
// Free-running: ONE s_barrier + one counted s_waitcnt per K-tile; stage t+2
// during tile t (ring-3 WAR-safe: slot's readers drained at end-of-(t-1));
// end-of-tile vmcnt(3) certifies t+1, t+2's 3 loads stay in flight.
// LDS layout (r2/r3-proven): line = 2 rows x 32 cols = 128B; 16B-slot
// within line: slot = ((r&1)*4 + lg) ^ ((r>>1)&7); staged via pre-inverse-
// swizzled global source + LINEAR gload_lds dest (rule 21).
// T1: bijective XCD swizzle, bm-fastest (concurrent blocks share B-panels).
// EPI 0: store bf16 g (regular: reread by GEMM2). EPI 1: h = silu(g)*acc
// (regular: reread by GEMM3). EPI 2: out = acc*wt (NT, never reread).
// ============================================================================
template<int EPI>
__global__ __launch_bounds__(512, 4) void gemm_nt(
    const uint16_t* __restrict__ A,
    const uint16_t* __restrict__ B,
    uint16_t* __restrict__ G,
    float* __restrict__ O,
    const float* __restrict__ Wt,
    int N, int K, int nbm)
{
  __shared__ __align__(16) uint16_t lds[3][12288];   // slot: A[0..8191] B[8192..12287]

  const int nwg = (int)gridDim.x;
  const int lid = ((int)blockIdx.x & 7) * (nwg >> 3) + ((int)blockIdx.x >> 3);
  const int bm = lid % nbm, bn = lid / nbm;

  const int tid  = (int)threadIdx.x;
  const int lane = tid & 63, w = tid >> 6;
  const int wm = w >> 1, wn = w & 1;       // wave tile: rows wm*64, cols wn*64
  const int lr = lane & 15, lg = lane >> 4;

  // fragment read offsets (u16, slot-relative), r2/r3-proven swizzle
  int offA[4], offB[4];
#pragma unroll
  for (int m = 0; m < 4; ++m) {
    const int r = wm * 64 + m * 16 + lr;
    offA[m] = (r >> 1) * 64 + (((((r & 1) << 2) | lg) ^ ((r >> 1) & 7)) * 8);
  }
#pragma unroll
  for (int n = 0; n < 4; ++n) {
    const int r = wn * 64 + n * 16 + lr;
    offB[n] = 8192 + (r >> 1) * 64 + (((((r & 1) << 2) | lg) ^ ((r >> 1) & 7)) * 8);
  }

  // staging: inverse-swizzled global source, linear gload_lds dest (rule 21)
  const int su   = (tid & 7) ^ ((tid >> 3) & 7);
  const int sRow = 2 * (tid >> 3) + (su >> 2);
  const int sCol = (su & 3) * 8;
  const uint16_t* aSrc = A + (size_t)(bm * 256 + sRow) * K + sCol;
  const uint16_t* bSrc = B + (size_t)(bn * 128 + sRow) * K + sCol;
  const size_t rowStepA = (size_t)128 * K;

#define STAGE(tt, s) do { \
    const uint16_t* _pa = aSrc + (size_t)(tt) * 32; \
    gload16(_pa,            &lds[s][tid * 8]); \
    gload16(_pa + rowStepA, &lds[s][4096 + tid * 8]); \
    gload16(bSrc + (size_t)(tt) * 32, &lds[s][8192 + tid * 8]); \
  } while (0)

  f32x4 acc[4][4];
#pragma unroll
  for (int m = 0; m < 4; ++m)
#pragma unroll
    for (int n = 0; n < 4; ++n)
#pragma unroll
      for (int j = 0; j < 4; ++j) acc[m][n][j] = 0.f;

  const int nk = K >> 5;

  // prologue: stage tiles 0,1; certify tile 0 (tile 1's 3 loads in flight)
  STAGE(0, 0);
  STAGE(1, 1);
  asm volatile("s_waitcnt vmcnt(3)" ::: "memory");
  __builtin_amdgcn_s_barrier();

  for (int t = 0; t < nk; ++t) {
    const uint16_t* S = &lds[t % 3][0];

    if (t + 2 < nk) STAGE(t + 2, (t + 2) % 3);

    short8 av[4], bv[4];
#pragma unroll
    for (int m = 0; m < 4; ++m) av[m] = *(const short8*)&S[offA[m]];
#pragma unroll
    for (int n = 0; n < 4; ++n) bv[n] = *(const short8*)&S[offB[n]];

    __builtin_amdgcn_s_setprio(1);
#pragma unroll
    for (int m = 0; m < 4; ++m)
#pragma unroll
      for (int n = 0; n < 4; ++n)
        acc[m][n] = __builtin_amdgcn_mfma_f32_16x16x32_bf16(av[m], bv[n], acc[m][n], 0, 0, 0);
    __builtin_amdgcn_s_setprio(0);

    // certify tile t+1; keep t+2's loads in flight (never drain mid-loop)
    if (t + 2 < nk) { asm volatile("s_waitcnt vmcnt(3)" ::: "memory"); }
    else            { asm volatile("s_waitcnt vmcnt(0)" ::: "memory"); }
    __builtin_amdgcn_s_barrier();
  }
#undef STAGE

  // epilogue (16x16 C/D): col = lane&15, row = (lane>>4)*4 + reg [m89]
  const int row0 = bm * 256 + wm * 64, col0 = bn * 128 + wn * 64;
#pragma unroll
  for (int m = 0; m < 4; ++m)
#pragma unroll
    for (int n = 0; n < 4; ++n) {
      const int c  = col0 + n * 16 + lr;
      const int rb = row0 + m * 16 + lg * 4;
#pragma unroll
      for (int j = 0; j < 4; ++j) {
        const int r = rb + j;
        const float v = acc[m][n][j];
        if constexpr (EPI == 0) {
          G[(size_t)r * N + c] = f2bf(v);
        } else if constexpr (EPI == 1) {
          float gf = bf2f(G[(size_t)r * N + c]);
          float h = gf / (1.f + __expf(-gf)) * v;
          G[(size_t)r * N + c] = f2bf(h);
        } else {
          __builtin_nontemporal_store(v * Wt[r], &O[(size_t)r * N + c]);
        }
      }
    }
}

extern "C" void kernel_launch(void* const* d_in, const int* in_sizes, int n_in,
                              void* d_out, int out_size, void* d_ws, size_t ws_size,
                              hipStream_t stream) {
  const float* x   = (const float*)d_in[0];
  const float* Wg  = (const float*)d_in[1];
  const float* Wu  = (const float*)d_in[2];
  const float* Wd  = (const float*)d_in[3];
  const int*   top = (const int*)d_in[4];
  const float* wt  = (const float*)d_in[5];
  float* out = (float*)d_out;

  const size_t NE_X = (size_t)NSEL * HIDDEN;
  const size_t NE_W = (size_t)INTER * HIDDEN;
  if (ws_size < (NE_X + 3 * NE_W) * sizeof(uint16_t)) return;

  uint16_t* xs = (uint16_t*)d_ws;
  uint16_t* w1 = xs + NE_X;
  uint16_t* w2 = w1 + NE_W;
  uint16_t* gh = w2 + NE_W;

  const int WBLK = (int)(NE_W / (256 * 8));
  const int nbm  = NSEL / 256;      // 16
  const int nbn1 = INTER / 128;     // 112
  const int nbn2 = HIDDEN / 128;    // 32

  cvt_f32_bf16<<<WBLK, 256, 0, stream>>>(Wg, w1);
  cvt_f32_bf16<<<WBLK, 256, 0, stream>>>(Wu, w2);
  gather_cast<<<NSEL, 256, 0, stream>>>(x, top, xs);

  // gate: g = x_sel * Wg^T -> gh (bf16)
  gemm_nt<0><<<nbm * nbn1, 512, 0, stream>>>(xs, w1, gh, nullptr, nullptr,
                                             INTER, HIDDEN, nbm);
  // Wd -> w1 (after gate GEMM consumed Wg; stream-ordered)
  cvt_f32_bf16<<<WBLK, 256, 0, stream>>>(Wd, w1);
  // up + SwiGLU: h = silu(g) * (x_sel * Wu^T) -> gh in place
  gemm_nt<1><<<nbm * nbn1, 512, 0, stream>>>(xs, w2, gh, nullptr, nullptr,
                                             INTER, HIDDEN, nbm);
  // down + routing weight: out = (h * Wd^T) * weight[:,None]
  gemm_nt<2><<<nbm * nbn2, 512, 0, stream>>>(gh, w1, nullptr, out, wt,
                                             HIDDEN, INTER, nbm);
}

// Round 7
// 1649.117 us; speedup vs baseline: 1.2171x; 1.0535x over previous
//
#include <hip/hip_runtime.h>
#include <hip/hip_bf16.h>
#include <stdint.h>

#define HIDDEN 4096
#define INTER  14336
#define NSEL   4096

using short8 = __attribute__((ext_vector_type(8))) short;
using f32x4  = __attribute__((ext_vector_type(4))) float;

__device__ __forceinline__ uint16_t f2bf(float f) {
  uint32_t u = __float_as_uint(f);
  uint32_t r = (u + 0x7FFFu + ((u >> 16) & 1u)) >> 16;
  return (uint16_t)r;
}
__device__ __forceinline__ float bf2f(uint16_t h) {
  return __uint_as_float(((uint32_t)h) << 16);
}
__device__ __forceinline__ uint32_t pack2(float lo, float hi) {
  return (uint32_t)f2bf(lo) | ((uint32_t)f2bf(hi) << 16);
}

// ---- fp32 -> bf16 conversion, 8 elems/thread (standalone, for Wg) ----
__global__ void cvt_f32_bf16(const float* __restrict__ in, uint16_t* __restrict__ out) {
  size_t i = ((size_t)blockIdx.x * 256 + threadIdx.x) * 8;
  float4 a = *(const float4*)(in + i);
  float4 b = *(const float4*)(in + i + 4);
  uint4 v;
  v.x = pack2(a.x, a.y); v.y = pack2(a.z, a.w);
  v.z = pack2(b.x, b.y); v.w = pack2(b.z, b.w);
  *(uint4*)(out + i) = v;
}

// ---- gather selected tokens + cast to bf16 ----
__global__ void gather_cast(const float* __restrict__ x, const int* __restrict__ idx,
                            uint16_t* __restrict__ xs) {
  const int n = blockIdx.x;
  const int t = threadIdx.x;
  const size_t s = (size_t)idx[n] * HIDDEN + (size_t)t * 16;
  const size_t d = (size_t)n * HIDDEN + (size_t)t * 16;
  const float4* sp = (const float4*)(x + s);
  float4 f0 = sp[0], f1 = sp[1], f2 = sp[2], f3 = sp[3];
  uint4 v0, v1;
  v0.x = pack2(f0.x, f0.y); v0.y = pack2(f0.z, f0.w);
  v0.z = pack2(f1.x, f1.y); v0.w = pack2(f1.z, f1.w);
  v1.x = pack2(f2.x, f2.y); v1.y = pack2(f2.z, f2.w);
  v1.z = pack2(f3.x, f3.y); v1.w = pack2(f3.z, f3.w);
  *(uint4*)(xs + d)     = v0;
  *(uint4*)(xs + d + 8) = v1;
}

__device__ __forceinline__ void gload16(const void* g, void* l) {
  __builtin_amdgcn_global_load_lds(
      (const __attribute__((address_space(1))) void*)g,
      (__attribute__((address_space(3))) void*)l, 16, 0, 0);
}

// ============================================================================
// NT GEMM: C[M][N] = A[M][K]*B[N][K]^T, bf16 in, fp32 acc.
// 256x256 block tile, BK=32, 8 waves (2M x 4N) of 128x64, 512 threads.
// Geometry change vs r6 (which was LDS-pipe-bound at ~68%): 128x64 wave
// tiles cut ds_reads/MFMA 0.5 -> 0.375 (-25%) and 256x256 block cuts
// staging-writes/FLOP by 33%. acc = 8x4 16x16 frags (128 AGPR).
// Ring-3 LDS (3 x (A 16KB + B 16KB) = 96 KiB), 1 block/CU, free-running:
// ONE s_barrier + one counted s_waitcnt per K-tile; stage t+2 during t
// (never the slot being read); end-of-tile vmcnt(4) certifies t+1 while
// t+2's 4 loads stay in flight (never drains mid-loop).
// LDS swizzle (r2/r3/r6 measured-ZERO conflicts): line = 2 rows x 32 cols
// = 128B; 16B-slot = ((r&1)*4 + lg) ^ ((r>>1)&7); applied via pre-inverse-
// swizzled GLOBAL source + LINEAR gload_lds dest (rule 21) + swizzled read.
// T1: bijective XCD swizzle over the gemm sub-grid, bm-fastest.
// FUSED CVT TAIL: blocks >= nGemm convert fp32->bf16 (next GEMM's weight;
// only consumed by the NEXT kernel launch -> race-free). Kills the serial
// cvt passes between GEMMs.
// EPI 0: store bf16 g. EPI 1: h = silu(g)*acc overwrite. EPI 2: out=acc*wt.
// ============================================================================
template<int EPI>
__global__ __launch_bounds__(512, 2) void gemm_nt(
    const uint16_t* __restrict__ A,
    const uint16_t* __restrict__ B,
    uint16_t* __restrict__ G,
    float* __restrict__ O,
    const float* __restrict__ Wt,
    int N, int K, int nbm, int nGemm,
    const float* __restrict__ cvtIn, uint16_t* __restrict__ cvtOut)
{
  __shared__ __align__(16) uint16_t lds[3][16384];  // slot: A[0..8191] B[8192..16383]

  const int bid = (int)blockIdx.x;
  const int tid = (int)threadIdx.x;

  // ---- fused cvt tail (fp32 -> bf16, 16 elems/thread) ----
  if (bid >= nGemm) {
    const int cb = bid - nGemm;
    const size_t base = ((size_t)cb * 512 + tid) * 16;
#pragma unroll
    for (int h = 0; h < 2; ++h) {
      const float4 a = *(const float4*)(cvtIn + base + h * 8);
      const float4 b = *(const float4*)(cvtIn + base + h * 8 + 4);
      uint4 v;
      v.x = pack2(a.x, a.y); v.y = pack2(a.z, a.w);
      v.z = pack2(b.x, b.y); v.w = pack2(b.z, b.w);
      *(uint4*)(cvtOut + base + h * 8) = v;
    }
    return;
  }

  // ---- T1 XCD swizzle over gemm sub-grid (nGemm % 8 == 0) ----
  const int lid = (bid & 7) * (nGemm >> 3) + (bid >> 3);
  const int bm = lid % nbm, bn = lid / nbm;

  const int lane = tid & 63, w = tid >> 6;
  const int wm = w >> 2, wn = w & 3;       // wave tile: rows wm*128, cols wn*64
  const int lr = lane & 15, lg = lane >> 4;

  // fragment read offsets (u16, slot-relative), proven-zero swizzle
  int offA[8], offB[4];
#pragma unroll
  for (int m = 0; m < 8; ++m) {
    const int r = wm * 128 + m * 16 + lr;
    offA[m] = (r >> 1) * 64 + (((((r & 1) << 2) | lg) ^ ((r >> 1) & 7)) * 8);
  }
#pragma unroll
  for (int n = 0; n < 4; ++n) {
    const int r = wn * 64 + n * 16 + lr;
    offB[n] = 8192 + (r >> 1) * 64 + (((((r & 1) << 2) | lg) ^ ((r >> 1) & 7)) * 8);
  }

  // staging: inverse-swizzled global source, linear gload_lds dest (rule 21)
  const int su   = (tid & 7) ^ ((tid >> 3) & 7);
  const int sRow = 2 * (tid >> 3) + (su >> 2);
  const int sCol = (su & 3) * 8;
  const uint16_t* aSrc = A + (size_t)(bm * 256 + sRow) * K + sCol;
  const uint16_t* bSrc = B + (size_t)(bn * 256 + sRow) * K + sCol;
  const size_t rowStep = (size_t)128 * K;

#define STAGE(tt, s) do { \
    const uint16_t* _pa = aSrc + (size_t)(tt) * 32; \
    const uint16_t* _pb = bSrc + (size_t)(tt) * 32; \
    gload16(_pa,           &lds[s][tid * 8]); \
    gload16(_pa + rowStep, &lds[s][4096 + tid * 8]); \
    gload16(_pb,           &lds[s][8192 + tid * 8]); \
    gload16(_pb + rowStep, &lds[s][12288 + tid * 8]); \
  } while (0)

  f32x4 acc[8][4];
#pragma unroll
  for (int m = 0; m < 8; ++m)
#pragma unroll
    for (int n = 0; n < 4; ++n)
#pragma unroll
      for (int j = 0; j < 4; ++j) acc[m][n][j] = 0.f;

  const int nk = K >> 5;

  // prologue: stage tiles 0,1; certify tile 0 (tile 1's 4 loads in flight)
  STAGE(0, 0);
  STAGE(1, 1);
  asm volatile("s_waitcnt vmcnt(4)" ::: "memory");
  __builtin_amdgcn_s_barrier();

  for (int t = 0; t < nk; ++t) {
    const uint16_t* S = &lds[t % 3][0];

    if (t + 2 < nk) STAGE(t + 2, (t + 2) % 3);

    short8 av[4], av2[4], bv[4];
#pragma unroll
    for (int m = 0; m < 4; ++m) av[m] = *(const short8*)&S[offA[m]];
#pragma unroll
    for (int n = 0; n < 4; ++n) bv[n] = *(const short8*)&S[offB[n]];

    __builtin_amdgcn_s_setprio(1);
#pragma unroll
    for (int m = 0; m < 4; ++m)
#pragma unroll
      for (int n = 0; n < 4; ++n)
        acc[m][n] = __builtin_amdgcn_mfma_f32_16x16x32_bf16(av[m], bv[n], acc[m][n], 0, 0, 0);
    __builtin_amdgcn_s_setprio(0);

#pragma unroll
    for (int m = 0; m < 4; ++m) av2[m] = *(const short8*)&S[offA[4 + m]];

    __builtin_amdgcn_s_setprio(1);
#pragma unroll
    for (int m = 0; m < 4; ++m)
#pragma unroll
      for (int n = 0; n < 4; ++n)
        acc[4 + m][n] = __builtin_amdgcn_mfma_f32_16x16x32_bf16(av2[m], bv[n], acc[4 + m][n], 0, 0, 0);
    __builtin_amdgcn_s_setprio(0);

    // certify tile t+1; keep t+2's loads in flight (never drain mid-loop)
    if (t + 2 < nk) { asm volatile("s_waitcnt vmcnt(4)" ::: "memory"); }
    else            { asm volatile("s_waitcnt vmcnt(0)" ::: "memory"); }
    __builtin_amdgcn_s_barrier();
  }
#undef STAGE

  // epilogue (16x16 C/D): col = lane&15, row = (lane>>4)*4 + reg [m89]
  const int row0 = bm * 256 + wm * 128, col0 = bn * 256 + wn * 64;
#pragma unroll
  for (int m = 0; m < 8; ++m)
#pragma unroll
    for (int n = 0; n < 4; ++n) {
      const int c  = col0 + n * 16 + lr;
      const int rb = row0 + m * 16 + lg * 4;
#pragma unroll
      for (int j = 0; j < 4; ++j) {
        const int r = rb + j;
        const float v = acc[m][n][j];
        if constexpr (EPI == 0) {
          G[(size_t)r * N + c] = f2bf(v);
        } else if constexpr (EPI == 1) {
          float gf = bf2f(G[(size_t)r * N + c]);
          float h = gf / (1.f + __expf(-gf)) * v;
          G[(size_t)r * N + c] = f2bf(h);
        } else {
          __builtin_nontemporal_store(v * Wt[r], &O[(size_t)r * N + c]);
        }
      }
    }
}

extern "C" void kernel_launch(void* const* d_in, const int* in_sizes, int n_in,
                              void* d_out, int out_size, void* d_ws, size_t ws_size,
                              hipStream_t stream) {
  const float* x   = (const float*)d_in[0];
  const float* Wg  = (const float*)d_in[1];
  const float* Wu  = (const float*)d_in[2];
  const float* Wd  = (const float*)d_in[3];
  const int*   top = (const int*)d_in[4];
  const float* wt  = (const float*)d_in[5];
  float* out = (float*)d_out;

  const size_t NE_X = (size_t)NSEL * HIDDEN;
  const size_t NE_W = (size_t)INTER * HIDDEN;
  if (ws_size < (NE_X + 3 * NE_W) * sizeof(uint16_t)) return;

  uint16_t* xs = (uint16_t*)d_ws;
  uint16_t* w1 = xs + NE_X;
  uint16_t* w2 = w1 + NE_W;
  uint16_t* gh = w2 + NE_W;

  const int WBLK = (int)(NE_W / (256 * 8));      // 28672 (standalone cvt)
  const int NCVT = (int)(NE_W / (512 * 16));     // 7168  (fused cvt tail)
  const int nbm  = NSEL / 256;      // 16
  const int nbn1 = INTER / 256;     // 56
  const int nbn2 = HIDDEN / 256;    // 16
  const int ng1  = nbm * nbn1;      // 896
  const int ng2  = nbm * nbn2;      // 256

  cvt_f32_bf16<<<WBLK, 256, 0, stream>>>(Wg, w1);
  gather_cast<<<NSEL, 256, 0, stream>>>(x, top, xs);

  // gate: g = x_sel * Wg^T -> gh (bf16); tail converts Wu -> w2 for GEMM2
  gemm_nt<0><<<ng1 + NCVT, 512, 0, stream>>>(xs, w1, gh, nullptr, nullptr,
                                             INTER, HIDDEN, nbm, ng1, Wu, w2);
  // up + SwiGLU: h = silu(g) * (x_sel * Wu^T) -> gh; tail converts Wd -> w1
  gemm_nt<1><<<ng1 + NCVT, 512, 0, stream>>>(xs, w2, gh, nullptr, nullptr,
                                             INTER, HIDDEN, nbm, ng1, Wd, w1);
  // down + routing weight: out = (h * Wd^T) * weight[:,None]
  gemm_nt<2><<<ng2, 512, 0, stream>>>(gh, w1, nullptr, out, wt,
                                      HIDDEN, INTER, nbm, ng2, nullptr, nullptr);
}